// Round 11
// baseline (656.009 us; speedup 1.0000x reference)
//
#include <hip/hip_runtime.h>
#include <hip/hip_bf16.h>

typedef __bf16 bf16;
typedef __attribute__((ext_vector_type(8))) __bf16 bf16x8;
typedef __attribute__((ext_vector_type(4))) __bf16 bf16x4;
typedef __attribute__((ext_vector_type(4))) float floatx4;

#define HEADS 16
#define NTOK 49
#define MROWS (2048 * 49)        // 100352
#define TILE_E 1568              // 49*32 elems per (b,h) tile
#define LOGIT_MAX 4.6051702f     // ln(100)

// ---------------- helpers ----------------

__device__ __forceinline__ void gload16(const void* g, void* l) {
  __builtin_amdgcn_global_load_lds((const __attribute__((address_space(1))) void*)g,
                                   (__attribute__((address_space(3))) void*)l, 16, 0, 0);
}

// ---------------- fp32 -> bf16 convert (vectorized) ----------------

__global__ void cvt_x(const float* __restrict__ in, bf16* __restrict__ out, int n4) {
  int i = blockIdx.x * blockDim.x + threadIdx.x;
  const int stride = gridDim.x * blockDim.x;
  for (; i < n4; i += stride) {
    float4 v = ((const float4*)in)[i];
    bf16x4 o;
    o[0] = (bf16)v.x; o[1] = (bf16)v.y; o[2] = (bf16)v.z; o[3] = (bf16)v.w;
    *(bf16x4*)&out[(long)i * 4] = o;
  }
}

// out[c][r] = (bf16) in[r][c]   (weights -> B^T bf16)
__global__ void transpose_bf16(const float* __restrict__ in, bf16* __restrict__ out,
                               int R, int C) {
  int idx = blockIdx.x * blockDim.x + threadIdx.x;
  if (idx < R * C) {
    int r = idx / C, c = idx % C;
    out[(long)c * R + r] = (bf16)in[(long)r * C + c];
  }
}

// ---------------- CPB MLP: [169,2] -> relu([169,512]) -> [169,16] ----------------

__global__ void cpb_mlp(const float* __restrict__ w1, const float* __restrict__ b1,
                        const float* __restrict__ w2, float* __restrict__ out169) {
  const int r = blockIdx.x;          // 0..168
  const int ti = r / 13, tj = r % 13;
  float v0 = (float)(ti - 6) * (8.0f / 6.0f);
  float v1 = (float)(tj - 6) * (8.0f / 6.0f);
  float s0 = (v0 > 0.f) ? 1.f : ((v0 < 0.f) ? -1.f : 0.f);
  float s1 = (v1 > 0.f) ? 1.f : ((v1 < 0.f) ? -1.f : 0.f);
  const float t0 = s0 * log2f(fabsf(v0) + 1.0f) * (1.0f / 3.0f);  // log2(8)=3
  const float t1 = s1 * log2f(fabsf(v1) + 1.0f) * (1.0f / 3.0f);

  float acc[16];
#pragma unroll
  for (int h = 0; h < 16; ++h) acc[h] = 0.f;

  for (int c = threadIdx.x; c < 512; c += 64) {
    float hv = fmaxf(t0 * w1[c] + t1 * w1[512 + c] + b1[c], 0.f);
#pragma unroll
    for (int h = 0; h < 16; ++h) acc[h] += hv * w2[c * 16 + h];
  }
#pragma unroll
  for (int h = 0; h < 16; ++h) {
    float s = acc[h];
    for (int off = 32; off > 0; off >>= 1) s += __shfl_down(s, off);
    if (threadIdx.x == 0) out169[r * 16 + h] = s;
  }
}

// bias_sig: padded [16][64][52] fp32; [h][q][k] = 16*sigmoid(table[idx(q,k)][h]), 0 outside
__global__ void bias_expand(const float* __restrict__ out169, float* __restrict__ bias_sig) {
  int idx = blockIdx.x * blockDim.x + threadIdx.x;
  if (idx < 16 * 64 * 52) {
    int h = idx / 3328;
    int rem = idx % 3328;
    int q = rem / 52, k = rem % 52;
    float val = 0.f;
    if (q < 49 && k < 49) {
      int di = q / 7 - k / 7 + 6;
      int dj = q % 7 - k % 7 + 6;
      float v = out169[(di * 13 + dj) * 16 + h];
      val = 16.0f / (1.0f + expf(-v));
    }
    bias_sig[idx] = val;
  }
}

// ---------------- 128x128 bf16 MFMA GEMM, C = A[M,K] * BT[N,K]^T ----------------
// 4 waves (2x2), BK=64. A staged via global_load_lds into 16KB LDS (T2 swizzle);
// B fragments loaded DIRECTLY from global (weights are L2-resident) -- halves
// per-K-tile LDS traffic (96KB->48KB), lifting the LDS-BW cap on MfmaUtil
// from ~42% to ~83%. B loads issued before A staging so the pre-compute
// barrier drain covers their latency. Bijective XCD swizzle.
// EPI 0: packed per-(b,h) [49][32] Q/K/V tiles + q/v bias (hoisted). EPI 1: fp32 + bias.

__device__ __forceinline__ void stage_tile(const bf16* __restrict__ G, int ldg,
                                           bf16* lds, int w, int lane) {
#pragma unroll
  for (int j = 0; j < 4; ++j) {
    const int rr = w * 32 + j * 8;
    const int row = rr + (lane >> 3);
    const int slot = (lane & 7) ^ (lane >> 3);   // inverse swizzle on source
    gload16(G + (long)row * ldg + slot * 8, lds + rr * 64);
  }
}

template <int EPI>
__global__ __launch_bounds__(256, 3)
void gemm128(const bf16* __restrict__ A, const bf16* __restrict__ BT,
             void* __restrict__ Cout, const float* __restrict__ bias0,
             const float* __restrict__ bias1,
             bf16* __restrict__ Qp, bf16* __restrict__ Kp, bf16* __restrict__ Vp,
             int NT, int K, long N) {
  __shared__ bf16 AS[128][64];
  const int tid = threadIdx.x;
  const int lane = tid & 63, w = tid >> 6;
  const int l15 = lane & 15, g = lane >> 4;
  const int wm = w >> 1, wn = w & 1;

  // bijective XCD swizzle (grid % 8 == 0)
  int wg = blockIdx.x;
  wg = (wg & 7) * ((int)gridDim.x >> 3) + (wg >> 3);
  const long m0 = (long)(wg / NT) * 128;
  const long n0 = (long)(wg % NT) * 128;

  const bf16* Ab = A + m0 * K;
  // per-lane B row base: row = wn*64 + n*16 + l15, col offset g*8
  const bf16* Bw = BT + (n0 + wn * 64 + l15) * K + g * 8;

  floatx4 acc[4][4] = {};

  const int NKT = K >> 6;
  for (int kt = 0; kt < NKT; ++kt) {
    __syncthreads();                         // prev compute done before overwrite
    // B fragments direct from global (L2-resident weights); issued first so the
    // barrier drain below covers them together with the A gload_lds.
    bf16x8 bfr[2][4];
#pragma unroll
    for (int t = 0; t < 2; ++t)
#pragma unroll
      for (int n = 0; n < 4; ++n)
        bfr[t][n] = *(const bf16x8*)(Bw + (long)n * 16 * K + kt * 64 + t * 32);
    stage_tile(Ab + kt * 64, K, &AS[0][0], w, lane);
    __syncthreads();                         // implies vmcnt(0): A tile + B frags resident
#pragma unroll
    for (int t = 0; t < 2; ++t) {
      const int s = t * 4 + g;               // logical 16B slot within row
      bf16x8 af[4];
#pragma unroll
      for (int m = 0; m < 4; ++m) {
        const int row = wm * 64 + m * 16 + l15;
        af[m] = *(const bf16x8*)&AS[row][(s ^ (row & 7)) * 8];
      }
#pragma unroll
      for (int m = 0; m < 4; ++m)
#pragma unroll
        for (int n = 0; n < 4; ++n)
          acc[m][n] = __builtin_amdgcn_mfma_f32_16x16x32_bf16(af[m], bfr[t][n], acc[m][n], 0, 0, 0);
    }
  }

  // ---- epilogue ----
  if (EPI == 0) {
    // whole 128-wide n-tile lies in one of Q/K/V (boundaries at 512)
    const int mat = (int)(n0 >> 9);                       // uniform
    bf16* const dst = (mat == 0) ? Qp : ((mat == 1) ? Kp : Vp);
    float badd4[4];
    unsigned off4[4];
#pragma unroll
    for (int n = 0; n < 4; ++n) {
      const int coln = (int)n0 + wn * 64 + n * 16;        // scalar per n
      const int hh = (coln >> 5) & 15;
      const int d = (coln & 16) + l15;
      off4[n] = (unsigned)hh * TILE_E + d;
      badd4[n] = (mat == 0) ? bias0[coln + l15]
               : ((mat == 2) ? bias1[coln + l15 - 1024] : 0.0f);
    }
#pragma unroll
    for (int m = 0; m < 4; ++m) {
#pragma unroll
      for (int r = 0; r < 4; ++r) {
        const unsigned row = (unsigned)m0 + wm * 64 + m * 16 + g * 4 + r;
        const unsigned b = row / 49u;                     // magic-mul div
        const unsigned nr = row - b * 49u;
        const unsigned ebase = b * (16u * TILE_E) + nr * 32u;
#pragma unroll
        for (int n = 0; n < 4; ++n)
          dst[ebase + off4[n]] = (bf16)(acc[m][n][r] + badd4[n]);
      }
    }
  } else {
#pragma unroll
    for (int m = 0; m < 4; ++m) {
#pragma unroll
      for (int n = 0; n < 4; ++n) {
        const long col = n0 + wn * 64 + n * 16 + l15;
        const float badd = bias0[col];
#pragma unroll
        for (int r = 0; r < 4; ++r) {
          const long row = m0 + wm * 64 + m * 16 + g * 4 + r;
          ((float*)Cout)[row * N + col] = acc[m][n][r] + badd;
        }
      }
    }
  }
}

// ---------------- MFMA window attention v5: packed tiles + vectorized O stores ----------------
// 1 wave per (b,h). All global loads issued at entry; K/Q normalized up-front;
// P never leaves registers (sigma trick). O is transposed through the freed V-LDS
// buffer (rows padded to 40 elems) and stored as bf16x8 (16B/lane, full 64B segments).

__global__ __launch_bounds__(256)
void attn_mfma(const bf16* __restrict__ Qa, const bf16* __restrict__ Ka,
               const bf16* __restrict__ Va, const float* __restrict__ bias_sig,
               const float* __restrict__ logit_scale, bf16* __restrict__ aout) {
  __shared__ __align__(16) bf16 Vlds[4][2048];
  const int tid = threadIdx.x;
  const int wave = tid >> 6, lane = tid & 63;
  const int l15 = lane & 15, g = lane >> 4;
  const int bh = blockIdx.x * 4 + wave;    // b*16 + h
  const int h = bh & 15;
  const long tbase = (long)bh * TILE_E;
  const bf16* Qt = Qa + tbase;
  const bf16* Kt = Ka + tbase;
  const bf16* Vt = Va + tbase;
  bf16* VL = Vlds[wave];

  // ---- issue ALL global loads up-front (independent, in-flight together) ----
#pragma unroll
  for (int j = 0; j < 4; ++j)
    gload16(Vt + j * 512 + lane * 8, VL + j * 512);

  bf16x8 kraw[4], qraw[4];
#pragma unroll
  for (int t = 0; t < 4; ++t)
    kraw[t] = *(const bf16x8*)(Kt + (t * 16 + l15) * 32 + g * 8);
#pragma unroll
  for (int t = 0; t < 4; ++t)
    qraw[t] = *(const bf16x8*)(Qt + (t * 16 + l15) * 32 + g * 8);

  const float scale = __expf(fminf(logit_scale[h], LOGIT_MAX));

  // ---- normalize K and Q in-register (row sum via 2 shuffles) ----
  bf16x8 kf[4], qf[4];
#pragma unroll
  for (int t = 0; t < 4; ++t) {
    float fv[8], ss = 0.f;
#pragma unroll
    for (int j = 0; j < 8; ++j) { fv[j] = (float)kraw[t][j]; ss += fv[j] * fv[j]; }
    ss += __shfl_xor(ss, 16);
    ss += __shfl_xor(ss, 32);
    const float rk = rsqrtf(fmaxf(ss, 1e-12f));
#pragma unroll
    for (int j = 0; j < 8; ++j) kf[t][j] = (bf16)(fv[j] * rk);
  }
#pragma unroll
  for (int t = 0; t < 4; ++t) {
    float fv[8], ss = 0.f;
#pragma unroll
    for (int j = 0; j < 8; ++j) { fv[j] = (float)qraw[t][j]; ss += fv[j] * fv[j]; }
    ss += __shfl_xor(ss, 16);
    ss += __shfl_xor(ss, 32);
    const float rq = rsqrtf(fmaxf(ss, 1e-12f));
#pragma unroll
    for (int j = 0; j < 8; ++j) qf[t][j] = (bf16)(fv[j] * rq);
  }

  // ---- V^T fragments from LDS with k-order sigma(g,i)=t*32+16*(i>=4)+4g+(i&3) ----
  asm volatile("s_waitcnt vmcnt(0)" ::: "memory");
  __builtin_amdgcn_sched_barrier(0);
  bf16x8 vf[2][2];
#pragma unroll
  for (int dt = 0; dt < 2; ++dt)
#pragma unroll
    for (int t = 0; t < 2; ++t)
#pragma unroll
      for (int i = 0; i < 8; ++i) {
        const int kk = t * 32 + (i >> 2) * 16 + g * 4 + (i & 3);
        vf[dt][t][i] = VL[kk * 32 + dt * 16 + l15];
      }
  // VL is now free: reused below as the O transpose buffer, rows padded to 40.

  const floatx4 zero = {};

#pragma unroll
  for (int qt = 0; qt < 4; ++qt) {
    const int qrow = qt * 16 + l15;

    float4 b4[4];
#pragma unroll
    for (int kt = 0; kt < 4; ++kt)
      b4[kt] = *(const float4*)(bias_sig + h * 3328 + qrow * 52 + kt * 16 + g * 4);

    // S^T: lane holds S[q=l15][k=kt*16+4g+reg]
    floatx4 st[4];
#pragma unroll
    for (int kt = 0; kt < 4; ++kt)
      st[kt] = __builtin_amdgcn_mfma_f32_16x16x32_bf16(kf[kt], qf[qt], zero, 0, 0, 0);

    float sv[4][4];
    float m = -1e30f;
#pragma unroll
    for (int kt = 0; kt < 4; ++kt)
#pragma unroll
      for (int r = 0; r < 4; ++r) {
        const int k = kt * 16 + g * 4 + r;
        const float s = (k < NTOK) ? st[kt][r] * scale + ((const float*)&b4[kt])[r] : -1e30f;
        sv[kt][r] = s;
        m = fmaxf(m, s);
      }
    m = fmaxf(m, __shfl_xor(m, 16));
    m = fmaxf(m, __shfl_xor(m, 32));
    float l = 0.f;
#pragma unroll
    for (int kt = 0; kt < 4; ++kt)
#pragma unroll
      for (int r = 0; r < 4; ++r) {
        const float p = __expf(sv[kt][r] - m);
        sv[kt][r] = p;
        l += p;
      }
    l += __shfl_xor(l, 16);
    l += __shfl_xor(l, 32);
    const float inv = 1.0f / l;

    // P as A-fragments directly in registers (same sigma as vf)
    bf16x8 pa[2];
#pragma unroll
    for (int t = 0; t < 2; ++t)
#pragma unroll
      for (int i = 0; i < 8; ++i)
        pa[t][i] = (bf16)(sv[2 * t + (i >> 2)][i & 3] * inv);

    floatx4 ot[2] = {};
#pragma unroll
    for (int dt = 0; dt < 2; ++dt)
#pragma unroll
      for (int t = 0; t < 2; ++t)
        ot[dt] = __builtin_amdgcn_mfma_f32_16x16x32_bf16(pa[t], vf[dt][t], ot[dt], 0, 0, 0);

    // scatter O into LDS transpose buffer (per-wave private, no barrier needed)
#pragma unroll
    for (int dt = 0; dt < 2; ++dt)
#pragma unroll
      for (int r = 0; r < 4; ++r) {
        const int q = qt * 16 + g * 4 + r;
        if (q < NTOK) VL[q * 40 + dt * 16 + l15] = (bf16)ot[dt][r];
      }
  }

  // ---- vectorized O store: 16B/lane, full 64B segments ----
  asm volatile("s_waitcnt lgkmcnt(0)" ::: "memory");
  __builtin_amdgcn_sched_barrier(0);
  const long obase = (long)(bh >> 4) * NTOK * 512 + h * 32;
#pragma unroll
  for (int j = 0; j < 4; ++j) {
    const int c = lane + 64 * j;           // row-chunk id, valid < 196
    if (c < 196) {
      const int row = c >> 2, part = c & 3;
      bf16x8 v = *(const bf16x8*)&VL[row * 40 + part * 8];
      *(bf16x8*)(aout + obase + (long)row * 512 + part * 8) = v;
    }
  }
}

// ---------------- launch ----------------

extern "C" void kernel_launch(void* const* d_in, const int* in_sizes, int n_in,
                              void* d_out, int out_size, void* d_ws, size_t ws_size,
                              hipStream_t stream) {
  (void)in_sizes; (void)n_in; (void)out_size; (void)ws_size;
  const float* x           = (const float*)d_in[0];
  const float* w_qkv       = (const float*)d_in[1];
  const float* q_bias      = (const float*)d_in[2];
  const float* v_bias      = (const float*)d_in[3];
  const float* logit_scale = (const float*)d_in[4];
  const float* cpb_w1      = (const float*)d_in[5];
  const float* cpb_b1      = (const float*)d_in[6];
  const float* cpb_w2      = (const float*)d_in[7];
  const float* proj_w      = (const float*)d_in[8];
  const float* proj_b      = (const float*)d_in[9];
  float* out = (float*)d_out;

  char* ws = (char*)d_ws;
  const size_t ARR_B  = 102760448;   // 32768*1568*2 = 100352*512*2
  const size_t WQT_B  = 1572864;     // 1536*512*2
  const size_t PJT_B  = 524288;      // 512*512*2
  const size_t T169_B = 10816;       // 169*16*4 (rounded)
  bf16*  Qa       = (bf16*)ws;
  bf16*  Ka       = (bf16*)(ws + ARR_B);
  bf16*  Va       = (bf16*)(ws + 2 * ARR_B);
  bf16*  xbf      = (bf16*)(ws + 3 * ARR_B);           // x bf16, then attn_out (gemm1 A)
  bf16*  wqkvT    = (bf16*)(ws + 4 * ARR_B);
  bf16*  projT    = (bf16*)(ws + 4 * ARR_B + WQT_B);
  float* tab169   = (float*)(ws + 4 * ARR_B + WQT_B + PJT_B);
  float* bias_sig = (float*)(ws + 4 * ARR_B + WQT_B + PJT_B + T169_B);

  cvt_x<<<2048, 256, 0, stream>>>(x, xbf, MROWS * 512 / 4);
  transpose_bf16<<<3072, 256, 0, stream>>>(w_qkv, wqkvT, 512, 1536);
  transpose_bf16<<<1024, 256, 0, stream>>>(proj_w, projT, 512, 512);
  cpb_mlp<<<169, 64, 0, stream>>>(cpb_w1, cpb_b1, cpb_w2, tab169);
  bias_expand<<<208, 256, 0, stream>>>(tab169, bias_sig);

  gemm128<0><<<784 * 12, 256, 0, stream>>>(xbf, wqkvT, nullptr, q_bias, v_bias,
                                           Qa, Ka, Va, 12, 512, 1536);
  attn_mfma<<<8192, 256, 0, stream>>>(Qa, Ka, Va, bias_sig, logit_scale, xbf);
  gemm128<1><<<784 * 4, 256, 0, stream>>>(xbf, projT, out, proj_b, nullptr,
                                          nullptr, nullptr, nullptr, 4, 512, 512);
}

// Round 12
// 494.696 us; speedup vs baseline: 1.3261x; 1.3261x over previous
//
#include <hip/hip_runtime.h>
#include <hip/hip_bf16.h>

typedef __bf16 bf16;
typedef __attribute__((ext_vector_type(8))) __bf16 bf16x8;
typedef __attribute__((ext_vector_type(4))) __bf16 bf16x4;
typedef __attribute__((ext_vector_type(4))) float floatx4;

#define HEADS 16
#define NTOK 49
#define MROWS (2048 * 49)        // 100352
#define TILE_E 1568              // 49*32 elems per (b,h) tile
#define LOGIT_MAX 4.6051702f     // ln(100)

// ---------------- helpers ----------------

__device__ __forceinline__ void gload16(const void* g, void* l) {
  __builtin_amdgcn_global_load_lds((const __attribute__((address_space(1))) void*)g,
                                   (__attribute__((address_space(3))) void*)l, 16, 0, 0);
}

// ---------------- fp32 -> bf16 convert (vectorized) ----------------

__global__ void cvt_x(const float* __restrict__ in, bf16* __restrict__ out, int n4) {
  int i = blockIdx.x * blockDim.x + threadIdx.x;
  const int stride = gridDim.x * blockDim.x;
  for (; i < n4; i += stride) {
    float4 v = ((const float4*)in)[i];
    bf16x4 o;
    o[0] = (bf16)v.x; o[1] = (bf16)v.y; o[2] = (bf16)v.z; o[3] = (bf16)v.w;
    *(bf16x4*)&out[(long)i * 4] = o;
  }
}

// out[c][r] = (bf16) in[r][c]   (weights -> B^T bf16)
__global__ void transpose_bf16(const float* __restrict__ in, bf16* __restrict__ out,
                               int R, int C) {
  int idx = blockIdx.x * blockDim.x + threadIdx.x;
  if (idx < R * C) {
    int r = idx / C, c = idx % C;
    out[(long)c * R + r] = (bf16)in[(long)r * C + c];
  }
}

// ---------------- CPB MLP: [169,2] -> relu([169,512]) -> [169,16] ----------------

__global__ void cpb_mlp(const float* __restrict__ w1, const float* __restrict__ b1,
                        const float* __restrict__ w2, float* __restrict__ out169) {
  const int r = blockIdx.x;          // 0..168
  const int ti = r / 13, tj = r % 13;
  float v0 = (float)(ti - 6) * (8.0f / 6.0f);
  float v1 = (float)(tj - 6) * (8.0f / 6.0f);
  float s0 = (v0 > 0.f) ? 1.f : ((v0 < 0.f) ? -1.f : 0.f);
  float s1 = (v1 > 0.f) ? 1.f : ((v1 < 0.f) ? -1.f : 0.f);
  const float t0 = s0 * log2f(fabsf(v0) + 1.0f) * (1.0f / 3.0f);  // log2(8)=3
  const float t1 = s1 * log2f(fabsf(v1) + 1.0f) * (1.0f / 3.0f);

  float acc[16];
#pragma unroll
  for (int h = 0; h < 16; ++h) acc[h] = 0.f;

  for (int c = threadIdx.x; c < 512; c += 64) {
    float hv = fmaxf(t0 * w1[c] + t1 * w1[512 + c] + b1[c], 0.f);
#pragma unroll
    for (int h = 0; h < 16; ++h) acc[h] += hv * w2[c * 16 + h];
  }
#pragma unroll
  for (int h = 0; h < 16; ++h) {
    float s = acc[h];
    for (int off = 32; off > 0; off >>= 1) s += __shfl_down(s, off);
    if (threadIdx.x == 0) out169[r * 16 + h] = s;
  }
}

// bias_sig: padded [16][64][52] fp32; [h][q][k] = 16*sigmoid(table[idx(q,k)][h]), 0 outside
__global__ void bias_expand(const float* __restrict__ out169, float* __restrict__ bias_sig) {
  int idx = blockIdx.x * blockDim.x + threadIdx.x;
  if (idx < 16 * 64 * 52) {
    int h = idx / 3328;
    int rem = idx % 3328;
    int q = rem / 52, k = rem % 52;
    float val = 0.f;
    if (q < 49 && k < 49) {
      int di = q / 7 - k / 7 + 6;
      int dj = q % 7 - k % 7 + 6;
      float v = out169[(di * 13 + dj) * 16 + h];
      val = 16.0f / (1.0f + expf(-v));
    }
    bias_sig[idx] = val;
  }
}

// ---------------- 256x128 fat-wave bf16 MFMA GEMM, C = A[M,K] * BT[N,K]^T ----------------
// 4 waves, each owning a 64x128 output strip (acc 4x8): per t a wave reads
// 4 A-frags + 8 B-frags = 12 ds_read_b128 feeding 32 MFMAs -> LDS bytes/MFMA
// drops 0.75->0.56 KB, lifting the LDS-read-BW cap on MfmaUtil (r10 model: 33%
// measured = the 2x2 cap). Staging via global_load_lds (r11 showed direct-global
// B on the critical path is a loss). T2 swizzle + bijective XCD swizzle as before.
// EPI 0: packed per-(b,h) [49][32] Q/K/V tiles + q/v bias. EPI 1: fp32 + bias.

template <int EPI>
__global__ __launch_bounds__(256, 2)
void gemmF(const bf16* __restrict__ A, const bf16* __restrict__ BT,
           void* __restrict__ Cout, const float* __restrict__ bias0,
           const float* __restrict__ bias1,
           bf16* __restrict__ Qp, bf16* __restrict__ Kp, bf16* __restrict__ Vp,
           int NT, int K, long N) {
  __shared__ bf16 AS[256][64];
  __shared__ bf16 BS[128][64];
  const int tid = threadIdx.x;
  const int lane = tid & 63, w = tid >> 6;   // wave w owns rows [w*64, w*64+64)
  const int l15 = lane & 15, g = lane >> 4;

  // bijective XCD swizzle (grid % 8 == 0)
  int wg = blockIdx.x;
  wg = (wg & 7) * ((int)gridDim.x >> 3) + (wg >> 3);
  const long m0 = (long)(wg / NT) * 256;
  const long n0 = (long)(wg % NT) * 128;

  const bf16* Ab = A + m0 * K;
  const bf16* Bb = BT + n0 * K;

  floatx4 acc[4][8] = {};

  const int NKT = K >> 6;
  for (int kt = 0; kt < NKT; ++kt) {
    __syncthreads();                         // prev compute done before overwrite
    // stage A (wave w: its own 64 rows, 8 instr) and B (32 rows, 4 instr)
#pragma unroll
    for (int j = 0; j < 8; ++j) {
      const int rr = w * 64 + j * 8;
      const int row = rr + (lane >> 3);
      const int slot = (lane & 7) ^ (lane >> 3);
      gload16(Ab + (long)row * K + kt * 64 + slot * 8, &AS[rr][0]);
    }
#pragma unroll
    for (int j = 0; j < 4; ++j) {
      const int rr = w * 32 + j * 8;
      const int row = rr + (lane >> 3);
      const int slot = (lane & 7) ^ (lane >> 3);
      gload16(Bb + (long)row * K + kt * 64 + slot * 8, &BS[rr][0]);
    }
    __syncthreads();                         // implies vmcnt(0): tiles resident
#pragma unroll
    for (int t = 0; t < 2; ++t) {
      const int s = t * 4 + g;               // logical 16B slot within row
      bf16x8 af[4], bfr[8];
#pragma unroll
      for (int m = 0; m < 4; ++m) {
        const int row = w * 64 + m * 16 + l15;
        af[m] = *(const bf16x8*)&AS[row][(s ^ (row & 7)) * 8];
      }
#pragma unroll
      for (int n = 0; n < 8; ++n) {
        const int row = n * 16 + l15;
        bfr[n] = *(const bf16x8*)&BS[row][(s ^ (row & 7)) * 8];
      }
#pragma unroll
      for (int m = 0; m < 4; ++m)
#pragma unroll
        for (int n = 0; n < 8; ++n)
          acc[m][n] = __builtin_amdgcn_mfma_f32_16x16x32_bf16(af[m], bfr[n], acc[m][n], 0, 0, 0);
    }
  }

  // ---- epilogue ----
  if (EPI == 0) {
    // whole 128-wide n-tile lies in one of Q/K/V (boundaries at 512)
    const int mat = (int)(n0 >> 9);                       // uniform
    bf16* const dst = (mat == 0) ? Qp : ((mat == 1) ? Kp : Vp);
    float badd8[8];
    unsigned off8[8];
#pragma unroll
    for (int n = 0; n < 8; ++n) {
      const int coln = (int)n0 + n * 16;                  // scalar per n
      const int hh = (coln >> 5) & 15;
      const int d = (coln & 16) + l15;
      off8[n] = (unsigned)hh * TILE_E + d;
      badd8[n] = (mat == 0) ? bias0[coln + l15]
               : ((mat == 2) ? bias1[coln + l15 - 1024] : 0.0f);
    }
#pragma unroll
    for (int m = 0; m < 4; ++m) {
#pragma unroll
      for (int r = 0; r < 4; ++r) {
        const unsigned row = (unsigned)m0 + w * 64 + m * 16 + g * 4 + r;
        const unsigned b = row / 49u;                     // magic-mul div
        const unsigned nr = row - b * 49u;
        const unsigned ebase = b * (16u * TILE_E) + nr * 32u;
#pragma unroll
        for (int n = 0; n < 8; ++n)
          dst[ebase + off8[n]] = (bf16)(acc[m][n][r] + badd8[n]);
      }
    }
  } else {
#pragma unroll
    for (int m = 0; m < 4; ++m) {
#pragma unroll
      for (int n = 0; n < 8; ++n) {
        const long col = n0 + n * 16 + l15;
        const float badd = bias0[col];
#pragma unroll
        for (int r = 0; r < 4; ++r) {
          const long row = m0 + w * 64 + m * 16 + g * 4 + r;
          ((float*)Cout)[row * N + col] = acc[m][n][r] + badd;
        }
      }
    }
  }
}

// ---------------- MFMA window attention v5: packed tiles + vectorized O stores ----------------
// 1 wave per (b,h). All global loads issued at entry; K/Q normalized up-front;
// P never leaves registers (sigma trick). O is transposed through the freed V-LDS
// buffer (rows padded to 40 elems) and stored as bf16x8 (16B/lane, full 64B segments).

__global__ __launch_bounds__(256)
void attn_mfma(const bf16* __restrict__ Qa, const bf16* __restrict__ Ka,
               const bf16* __restrict__ Va, const float* __restrict__ bias_sig,
               const float* __restrict__ logit_scale, bf16* __restrict__ aout) {
  __shared__ __align__(16) bf16 Vlds[4][2048];
  const int tid = threadIdx.x;
  const int wave = tid >> 6, lane = tid & 63;
  const int l15 = lane & 15, g = lane >> 4;
  const int bh = blockIdx.x * 4 + wave;    // b*16 + h
  const int h = bh & 15;
  const long tbase = (long)bh * TILE_E;
  const bf16* Qt = Qa + tbase;
  const bf16* Kt = Ka + tbase;
  const bf16* Vt = Va + tbase;
  bf16* VL = Vlds[wave];

  // ---- issue ALL global loads up-front (independent, in-flight together) ----
#pragma unroll
  for (int j = 0; j < 4; ++j)
    gload16(Vt + j * 512 + lane * 8, VL + j * 512);

  bf16x8 kraw[4], qraw[4];
#pragma unroll
  for (int t = 0; t < 4; ++t)
    kraw[t] = *(const bf16x8*)(Kt + (t * 16 + l15) * 32 + g * 8);
#pragma unroll
  for (int t = 0; t < 4; ++t)
    qraw[t] = *(const bf16x8*)(Qt + (t * 16 + l15) * 32 + g * 8);

  const float scale = __expf(fminf(logit_scale[h], LOGIT_MAX));

  // ---- normalize K and Q in-register (row sum via 2 shuffles) ----
  bf16x8 kf[4], qf[4];
#pragma unroll
  for (int t = 0; t < 4; ++t) {
    float fv[8], ss = 0.f;
#pragma unroll
    for (int j = 0; j < 8; ++j) { fv[j] = (float)kraw[t][j]; ss += fv[j] * fv[j]; }
    ss += __shfl_xor(ss, 16);
    ss += __shfl_xor(ss, 32);
    const float rk = rsqrtf(fmaxf(ss, 1e-12f));
#pragma unroll
    for (int j = 0; j < 8; ++j) kf[t][j] = (bf16)(fv[j] * rk);
  }
#pragma unroll
  for (int t = 0; t < 4; ++t) {
    float fv[8], ss = 0.f;
#pragma unroll
    for (int j = 0; j < 8; ++j) { fv[j] = (float)qraw[t][j]; ss += fv[j] * fv[j]; }
    ss += __shfl_xor(ss, 16);
    ss += __shfl_xor(ss, 32);
    const float rq = rsqrtf(fmaxf(ss, 1e-12f));
#pragma unroll
    for (int j = 0; j < 8; ++j) qf[t][j] = (bf16)(fv[j] * rq);
  }

  // ---- V^T fragments from LDS with k-order sigma(g,i)=t*32+16*(i>=4)+4g+(i&3) ----
  asm volatile("s_waitcnt vmcnt(0)" ::: "memory");
  __builtin_amdgcn_sched_barrier(0);
  bf16x8 vf[2][2];
#pragma unroll
  for (int dt = 0; dt < 2; ++dt)
#pragma unroll
    for (int t = 0; t < 2; ++t)
#pragma unroll
      for (int i = 0; i < 8; ++i) {
        const int kk = t * 32 + (i >> 2) * 16 + g * 4 + (i & 3);
        vf[dt][t][i] = VL[kk * 32 + dt * 16 + l15];
      }
  // VL is now free: reused below as the O transpose buffer, rows padded to 40.

  const floatx4 zero = {};

#pragma unroll
  for (int qt = 0; qt < 4; ++qt) {
    const int qrow = qt * 16 + l15;

    float4 b4[4];
#pragma unroll
    for (int kt = 0; kt < 4; ++kt)
      b4[kt] = *(const float4*)(bias_sig + h * 3328 + qrow * 52 + kt * 16 + g * 4);

    // S^T: lane holds S[q=l15][k=kt*16+4g+reg]
    floatx4 st[4];
#pragma unroll
    for (int kt = 0; kt < 4; ++kt)
      st[kt] = __builtin_amdgcn_mfma_f32_16x16x32_bf16(kf[kt], qf[qt], zero, 0, 0, 0);

    float sv[4][4];
    float m = -1e30f;
#pragma unroll
    for (int kt = 0; kt < 4; ++kt)
#pragma unroll
      for (int r = 0; r < 4; ++r) {
        const int k = kt * 16 + g * 4 + r;
        const float s = (k < NTOK) ? st[kt][r] * scale + ((const float*)&b4[kt])[r] : -1e30f;
        sv[kt][r] = s;
        m = fmaxf(m, s);
      }
    m = fmaxf(m, __shfl_xor(m, 16));
    m = fmaxf(m, __shfl_xor(m, 32));
    float l = 0.f;
#pragma unroll
    for (int kt = 0; kt < 4; ++kt)
#pragma unroll
      for (int r = 0; r < 4; ++r) {
        const float p = __expf(sv[kt][r] - m);
        sv[kt][r] = p;
        l += p;
      }
    l += __shfl_xor(l, 16);
    l += __shfl_xor(l, 32);
    const float inv = 1.0f / l;

    // P as A-fragments directly in registers (same sigma as vf)
    bf16x8 pa[2];
#pragma unroll
    for (int t = 0; t < 2; ++t)
#pragma unroll
      for (int i = 0; i < 8; ++i)
        pa[t][i] = (bf16)(sv[2 * t + (i >> 2)][i & 3] * inv);

    floatx4 ot[2] = {};
#pragma unroll
    for (int dt = 0; dt < 2; ++dt)
#pragma unroll
      for (int t = 0; t < 2; ++t)
        ot[dt] = __builtin_amdgcn_mfma_f32_16x16x32_bf16(pa[t], vf[dt][t], ot[dt], 0, 0, 0);

    // scatter O into LDS transpose buffer (per-wave private, no barrier needed)
#pragma unroll
    for (int dt = 0; dt < 2; ++dt)
#pragma unroll
      for (int r = 0; r < 4; ++r) {
        const int q = qt * 16 + g * 4 + r;
        if (q < NTOK) VL[q * 40 + dt * 16 + l15] = (bf16)ot[dt][r];
      }
  }

  // ---- vectorized O store: 16B/lane, full 64B segments ----
  asm volatile("s_waitcnt lgkmcnt(0)" ::: "memory");
  __builtin_amdgcn_sched_barrier(0);
  const long obase = (long)(bh >> 4) * NTOK * 512 + h * 32;
#pragma unroll
  for (int j = 0; j < 4; ++j) {
    const int c = lane + 64 * j;           // row-chunk id, valid < 196
    if (c < 196) {
      const int row = c >> 2, part = c & 3;
      bf16x8 v = *(const bf16x8*)&VL[row * 40 + part * 8];
      *(bf16x8*)(aout + obase + (long)row * 512 + part * 8) = v;
    }
  }
}

// ---------------- launch ----------------

extern "C" void kernel_launch(void* const* d_in, const int* in_sizes, int n_in,
                              void* d_out, int out_size, void* d_ws, size_t ws_size,
                              hipStream_t stream) {
  (void)in_sizes; (void)n_in; (void)out_size; (void)ws_size;
  const float* x           = (const float*)d_in[0];
  const float* w_qkv       = (const float*)d_in[1];
  const float* q_bias      = (const float*)d_in[2];
  const float* v_bias      = (const float*)d_in[3];
  const float* logit_scale = (const float*)d_in[4];
  const float* cpb_w1      = (const float*)d_in[5];
  const float* cpb_b1      = (const float*)d_in[6];
  const float* cpb_w2      = (const float*)d_in[7];
  const float* proj_w      = (const float*)d_in[8];
  const float* proj_b      = (const float*)d_in[9];
  float* out = (float*)d_out;

  char* ws = (char*)d_ws;
  const size_t ARR_B  = 102760448;   // 32768*1568*2 = 100352*512*2
  const size_t WQT_B  = 1572864;     // 1536*512*2
  const size_t PJT_B  = 524288;      // 512*512*2
  const size_t T169_B = 10816;       // 169*16*4 (rounded)
  bf16*  Qa       = (bf16*)ws;
  bf16*  Ka       = (bf16*)(ws + ARR_B);
  bf16*  Va       = (bf16*)(ws + 2 * ARR_B);
  bf16*  xbf      = (bf16*)(ws + 3 * ARR_B);           // x bf16, then attn_out (gemm1 A)
  bf16*  wqkvT    = (bf16*)(ws + 4 * ARR_B);
  bf16*  projT    = (bf16*)(ws + 4 * ARR_B + WQT_B);
  float* tab169   = (float*)(ws + 4 * ARR_B + WQT_B + PJT_B);
  float* bias_sig = (float*)(ws + 4 * ARR_B + WQT_B + PJT_B + T169_B);

  cvt_x<<<2048, 256, 0, stream>>>(x, xbf, MROWS * 512 / 4);
  transpose_bf16<<<3072, 256, 0, stream>>>(w_qkv, wqkvT, 512, 1536);
  transpose_bf16<<<1024, 256, 0, stream>>>(proj_w, projT, 512, 512);
  cpb_mlp<<<169, 64, 0, stream>>>(cpb_w1, cpb_b1, cpb_w2, tab169);
  bias_expand<<<208, 256, 0, stream>>>(tab169, bias_sig);

  gemmF<0><<<392 * 12, 256, 0, stream>>>(xbf, wqkvT, nullptr, q_bias, v_bias,
                                         Qa, Ka, Va, 12, 512, 1536);
  attn_mfma<<<8192, 256, 0, stream>>>(Qa, Ka, Va, bias_sig, logit_scale, xbf);
  gemmF<1><<<392 * 4, 256, 0, stream>>>(xbf, projT, out, proj_b, nullptr,
                                        nullptr, nullptr, nullptr, 4, 512, 512);
}

// Round 13
// 488.939 us; speedup vs baseline: 1.3417x; 1.0118x over previous
//
#include <hip/hip_runtime.h>
#include <hip/hip_bf16.h>

typedef __bf16 bf16;
typedef __attribute__((ext_vector_type(8))) __bf16 bf16x8;
typedef __attribute__((ext_vector_type(4))) __bf16 bf16x4;
typedef __attribute__((ext_vector_type(4))) float floatx4;

#define HEADS 16
#define NTOK 49
#define MROWS (2048 * 49)        // 100352
#define TILE_E 1568              // 49*32 elems per (b,h) tile
#define LOGIT_MAX 4.6051702f     // ln(100)

// ---------------- helpers ----------------

__device__ __forceinline__ void gload16(const void* g, void* l) {
  __builtin_amdgcn_global_load_lds((const __attribute__((address_space(1))) void*)g,
                                   (__attribute__((address_space(3))) void*)l, 16, 0, 0);
}

// ---------------- fp32 -> bf16 convert (vectorized) ----------------

__global__ void cvt_x(const float* __restrict__ in, bf16* __restrict__ out, int n4) {
  int i = blockIdx.x * blockDim.x + threadIdx.x;
  const int stride = gridDim.x * blockDim.x;
  for (; i < n4; i += stride) {
    float4 v = ((const float4*)in)[i];
    bf16x4 o;
    o[0] = (bf16)v.x; o[1] = (bf16)v.y; o[2] = (bf16)v.z; o[3] = (bf16)v.w;
    *(bf16x4*)&out[(long)i * 4] = o;
  }
}

// out[c][r] = (bf16) in[r][c]   (weights -> B^T bf16)
__global__ void transpose_bf16(const float* __restrict__ in, bf16* __restrict__ out,
                               int R, int C) {
  int idx = blockIdx.x * blockDim.x + threadIdx.x;
  if (idx < R * C) {
    int r = idx / C, c = idx % C;
    out[(long)c * R + r] = (bf16)in[(long)r * C + c];
  }
}

// ---------------- CPB MLP: [169,2] -> relu([169,512]) -> [169,16] ----------------

__global__ void cpb_mlp(const float* __restrict__ w1, const float* __restrict__ b1,
                        const float* __restrict__ w2, float* __restrict__ out169) {
  const int r = blockIdx.x;          // 0..168
  const int ti = r / 13, tj = r % 13;
  float v0 = (float)(ti - 6) * (8.0f / 6.0f);
  float v1 = (float)(tj - 6) * (8.0f / 6.0f);
  float s0 = (v0 > 0.f) ? 1.f : ((v0 < 0.f) ? -1.f : 0.f);
  float s1 = (v1 > 0.f) ? 1.f : ((v1 < 0.f) ? -1.f : 0.f);
  const float t0 = s0 * log2f(fabsf(v0) + 1.0f) * (1.0f / 3.0f);  // log2(8)=3
  const float t1 = s1 * log2f(fabsf(v1) + 1.0f) * (1.0f / 3.0f);

  float acc[16];
#pragma unroll
  for (int h = 0; h < 16; ++h) acc[h] = 0.f;

  for (int c = threadIdx.x; c < 512; c += 64) {
    float hv = fmaxf(t0 * w1[c] + t1 * w1[512 + c] + b1[c], 0.f);
#pragma unroll
    for (int h = 0; h < 16; ++h) acc[h] += hv * w2[c * 16 + h];
  }
#pragma unroll
  for (int h = 0; h < 16; ++h) {
    float s = acc[h];
    for (int off = 32; off > 0; off >>= 1) s += __shfl_down(s, off);
    if (threadIdx.x == 0) out169[r * 16 + h] = s;
  }
}

// bias_sig: padded [16][64][52] fp32; [h][q][k] = 16*sigmoid(table[idx(q,k)][h]), 0 outside
__global__ void bias_expand(const float* __restrict__ out169, float* __restrict__ bias_sig) {
  int idx = blockIdx.x * blockDim.x + threadIdx.x;
  if (idx < 16 * 64 * 52) {
    int h = idx / 3328;
    int rem = idx % 3328;
    int q = rem / 52, k = rem % 52;
    float val = 0.f;
    if (q < 49 && k < 49) {
      int di = q / 7 - k / 7 + 6;
      int dj = q % 7 - k % 7 + 6;
      float v = out169[(di * 13 + dj) * 16 + h];
      val = 16.0f / (1.0f + expf(-v));
    }
    bias_sig[idx] = val;
  }
}

// ---------------- 128x128 high-occupancy bf16 MFMA GEMM, C = A[M,K] * BT[N,K]^T ----------------
// r10 variant (best measured: 209us, MfmaUtil 32.6, conflicts 0). 4 waves (2x2),
// BK=64, single-buffered 32KB LDS -> 3+ blocks/CU; cross-block TLP hides the
// stage/drain (m114). T2 XOR swizzle; bijective XCD swizzle. Structure-tuning
// beyond this measured null (r3/r4/r11/r12) -- 2-phase stall ceiling (m233).
// EPI 0: packed per-(b,h) [49][32] Q/K/V tiles + q/v bias (hoisted). EPI 1: fp32 + bias.

__device__ __forceinline__ void stage_tile(const bf16* __restrict__ G, int ldg,
                                           bf16* lds, int w, int lane) {
#pragma unroll
  for (int j = 0; j < 4; ++j) {
    const int rr = w * 32 + j * 8;
    const int row = rr + (lane >> 3);
    const int slot = (lane & 7) ^ (lane >> 3);   // inverse swizzle on source
    gload16(G + (long)row * ldg + slot * 8, lds + rr * 64);
  }
}

template <int EPI>
__global__ __launch_bounds__(256, 4)
void gemm128(const bf16* __restrict__ A, const bf16* __restrict__ BT,
             void* __restrict__ Cout, const float* __restrict__ bias0,
             const float* __restrict__ bias1,
             bf16* __restrict__ Qp, bf16* __restrict__ Kp, bf16* __restrict__ Vp,
             int NT, int K, long N) {
  __shared__ bf16 AS[128][64];
  __shared__ bf16 BS[128][64];
  const int tid = threadIdx.x;
  const int lane = tid & 63, w = tid >> 6;
  const int l15 = lane & 15, g = lane >> 4;
  const int wm = w >> 1, wn = w & 1;

  // bijective XCD swizzle (grid % 8 == 0)
  int wg = blockIdx.x;
  wg = (wg & 7) * ((int)gridDim.x >> 3) + (wg >> 3);
  const long m0 = (long)(wg / NT) * 128;
  const long n0 = (long)(wg % NT) * 128;

  const bf16* Ab = A + m0 * K;
  const bf16* Bb = BT + n0 * K;

  floatx4 acc[4][4] = {};

  const int NKT = K >> 6;
  for (int kt = 0; kt < NKT; ++kt) {
    __syncthreads();                         // prev compute done before overwrite
    stage_tile(Ab + kt * 64, K, &AS[0][0], w, lane);
    stage_tile(Bb + kt * 64, K, &BS[0][0], w, lane);
    __syncthreads();                         // implies vmcnt(0): tile resident
#pragma unroll
    for (int t = 0; t < 2; ++t) {
      const int s = t * 4 + g;               // logical 16B slot within row
      bf16x8 af[4], bfr[4];
#pragma unroll
      for (int m = 0; m < 4; ++m) {
        const int row = wm * 64 + m * 16 + l15;
        af[m] = *(const bf16x8*)&AS[row][(s ^ (row & 7)) * 8];
      }
#pragma unroll
      for (int n = 0; n < 4; ++n) {
        const int row = wn * 64 + n * 16 + l15;
        bfr[n] = *(const bf16x8*)&BS[row][(s ^ (row & 7)) * 8];
      }
#pragma unroll
      for (int m = 0; m < 4; ++m)
#pragma unroll
        for (int n = 0; n < 4; ++n)
          acc[m][n] = __builtin_amdgcn_mfma_f32_16x16x32_bf16(af[m], bfr[n], acc[m][n], 0, 0, 0);
    }
  }

  // ---- epilogue ----
  if (EPI == 0) {
    // whole 128-wide n-tile lies in one of Q/K/V (boundaries at 512)
    const int mat = (int)(n0 >> 9);                       // uniform
    bf16* const dst = (mat == 0) ? Qp : ((mat == 1) ? Kp : Vp);
    float badd4[4];
    unsigned off4[4];
#pragma unroll
    for (int n = 0; n < 4; ++n) {
      const int coln = (int)n0 + wn * 64 + n * 16;        // scalar per n
      const int hh = (coln >> 5) & 15;
      const int d = (coln & 16) + l15;
      off4[n] = (unsigned)hh * TILE_E + d;
      badd4[n] = (mat == 0) ? bias0[coln + l15]
               : ((mat == 2) ? bias1[coln + l15 - 1024] : 0.0f);
    }
#pragma unroll
    for (int m = 0; m < 4; ++m) {
#pragma unroll
      for (int r = 0; r < 4; ++r) {
        const unsigned row = (unsigned)m0 + wm * 64 + m * 16 + g * 4 + r;
        const unsigned b = row / 49u;                     // magic-mul div
        const unsigned nr = row - b * 49u;
        const unsigned ebase = b * (16u * TILE_E) + nr * 32u;
#pragma unroll
        for (int n = 0; n < 4; ++n)
          dst[ebase + off4[n]] = (bf16)(acc[m][n][r] + badd4[n]);
      }
    }
  } else {
#pragma unroll
    for (int m = 0; m < 4; ++m) {
#pragma unroll
      for (int n = 0; n < 4; ++n) {
        const long col = n0 + wn * 64 + n * 16 + l15;
        const float badd = bias0[col];
#pragma unroll
        for (int r = 0; r < 4; ++r) {
          const long row = m0 + wm * 64 + m * 16 + g * 4 + r;
          ((float*)Cout)[row * N + col] = acc[m][n][r] + badd;
        }
      }
    }
  }
}

// ---------------- MFMA window attention v6: static-bound softmax (no max pass) ----------------
// 1 wave per (b,h). All global loads issued at entry; K/Q normalized up-front;
// P never leaves registers (sigma trick). Softmax uses the STATIC upper bound
// M = scale*1.02 + 16 (q,k are unit vectors -> st in [-1,1]; bias in [0,16]) --
// shift-invariant, so the 16-deep fmax chain + 2 shuffles per qt are deleted.
// O transposed through the freed V-LDS buffer, stored as bf16x8.

__global__ __launch_bounds__(256)
void attn_mfma(const bf16* __restrict__ Qa, const bf16* __restrict__ Ka,
               const bf16* __restrict__ Va, const float* __restrict__ bias_sig,
               const float* __restrict__ logit_scale, bf16* __restrict__ aout) {
  __shared__ __align__(16) bf16 Vlds[4][2048];
  const int tid = threadIdx.x;
  const int wave = tid >> 6, lane = tid & 63;
  const int l15 = lane & 15, g = lane >> 4;
  const int bh = blockIdx.x * 4 + wave;    // b*16 + h
  const int h = bh & 15;
  const long tbase = (long)bh * TILE_E;
  const bf16* Qt = Qa + tbase;
  const bf16* Kt = Ka + tbase;
  const bf16* Vt = Va + tbase;
  bf16* VL = Vlds[wave];

  // ---- issue ALL global loads up-front (independent, in-flight together) ----
#pragma unroll
  for (int j = 0; j < 4; ++j)
    gload16(Vt + j * 512 + lane * 8, VL + j * 512);

  bf16x8 kraw[4], qraw[4];
#pragma unroll
  for (int t = 0; t < 4; ++t)
    kraw[t] = *(const bf16x8*)(Kt + (t * 16 + l15) * 32 + g * 8);
#pragma unroll
  for (int t = 0; t < 4; ++t)
    qraw[t] = *(const bf16x8*)(Qt + (t * 16 + l15) * 32 + g * 8);

  const float scale = __expf(fminf(logit_scale[h], LOGIT_MAX));
  const float M = scale * 1.02f + 16.0f;   // static upper bound on s = st*scale + bias

  // ---- normalize K and Q in-register (row sum via 2 shuffles) ----
  bf16x8 kf[4], qf[4];
#pragma unroll
  for (int t = 0; t < 4; ++t) {
    float fv[8], ss = 0.f;
#pragma unroll
    for (int j = 0; j < 8; ++j) { fv[j] = (float)kraw[t][j]; ss += fv[j] * fv[j]; }
    ss += __shfl_xor(ss, 16);
    ss += __shfl_xor(ss, 32);
    const float rk = rsqrtf(fmaxf(ss, 1e-12f));
#pragma unroll
    for (int j = 0; j < 8; ++j) kf[t][j] = (bf16)(fv[j] * rk);
  }
#pragma unroll
  for (int t = 0; t < 4; ++t) {
    float fv[8], ss = 0.f;
#pragma unroll
    for (int j = 0; j < 8; ++j) { fv[j] = (float)qraw[t][j]; ss += fv[j] * fv[j]; }
    ss += __shfl_xor(ss, 16);
    ss += __shfl_xor(ss, 32);
    const float rq = rsqrtf(fmaxf(ss, 1e-12f));
#pragma unroll
    for (int j = 0; j < 8; ++j) qf[t][j] = (bf16)(fv[j] * rq);
  }

  // ---- V^T fragments from LDS with k-order sigma(g,i)=t*32+16*(i>=4)+4g+(i&3) ----
  asm volatile("s_waitcnt vmcnt(0)" ::: "memory");
  __builtin_amdgcn_sched_barrier(0);
  bf16x8 vf[2][2];
#pragma unroll
  for (int dt = 0; dt < 2; ++dt)
#pragma unroll
    for (int t = 0; t < 2; ++t)
#pragma unroll
      for (int i = 0; i < 8; ++i) {
        const int kk = t * 32 + (i >> 2) * 16 + g * 4 + (i & 3);
        vf[dt][t][i] = VL[kk * 32 + dt * 16 + l15];
      }
  // VL is now free: reused below as the O transpose buffer, rows padded to 40.

  const floatx4 zero = {};

#pragma unroll
  for (int qt = 0; qt < 4; ++qt) {
    const int qrow = qt * 16 + l15;

    float4 b4[4];
#pragma unroll
    for (int kt = 0; kt < 4; ++kt)
      b4[kt] = *(const float4*)(bias_sig + h * 3328 + qrow * 52 + kt * 16 + g * 4);

    // S^T: lane holds S[q=l15][k=kt*16+4g+reg]
    floatx4 st[4];
#pragma unroll
    for (int kt = 0; kt < 4; ++kt)
      st[kt] = __builtin_amdgcn_mfma_f32_16x16x32_bf16(kf[kt], qf[qt], zero, 0, 0, 0);

    // softmax with static bound M (no max pass; k>=49 lanes contribute exp(-inf)=0
    // via bias=0 & masked s = -1e30)
    float sv[4][4];
    float l = 0.f;
#pragma unroll
    for (int kt = 0; kt < 4; ++kt)
#pragma unroll
      for (int r = 0; r < 4; ++r) {
        const int k = kt * 16 + g * 4 + r;
        const float s = (k < NTOK) ? st[kt][r] * scale + ((const float*)&b4[kt])[r] - M
                                   : -87.0f;   // exp(-87) ~ 1e-38 ~ 0
        const float p = __expf(s);
        sv[kt][r] = p;
        l += p;
      }
    l += __shfl_xor(l, 16);
    l += __shfl_xor(l, 32);
    const float inv = 1.0f / l;

    // P as A-fragments directly in registers (same sigma as vf)
    bf16x8 pa[2];
#pragma unroll
    for (int t = 0; t < 2; ++t)
#pragma unroll
      for (int i = 0; i < 8; ++i)
        pa[t][i] = (bf16)(sv[2 * t + (i >> 2)][i & 3] * inv);

    floatx4 ot[2] = {};
#pragma unroll
    for (int dt = 0; dt < 2; ++dt)
#pragma unroll
      for (int t = 0; t < 2; ++t)
        ot[dt] = __builtin_amdgcn_mfma_f32_16x16x32_bf16(pa[t], vf[dt][t], ot[dt], 0, 0, 0);

    // scatter O into LDS transpose buffer (per-wave private, no barrier needed)
#pragma unroll
    for (int dt = 0; dt < 2; ++dt)
#pragma unroll
      for (int r = 0; r < 4; ++r) {
        const int q = qt * 16 + g * 4 + r;
        if (q < NTOK) VL[q * 40 + dt * 16 + l15] = (bf16)ot[dt][r];
      }
  }

  // ---- vectorized O store: 16B/lane, full 64B segments ----
  asm volatile("s_waitcnt lgkmcnt(0)" ::: "memory");
  __builtin_amdgcn_sched_barrier(0);
  const long obase = (long)(bh >> 4) * NTOK * 512 + h * 32;
#pragma unroll
  for (int j = 0; j < 4; ++j) {
    const int c = lane + 64 * j;           // row-chunk id, valid < 196
    if (c < 196) {
      const int row = c >> 2, part = c & 3;
      bf16x8 v = *(const bf16x8*)&VL[row * 40 + part * 8];
      *(bf16x8*)(aout + obase + (long)row * 512 + part * 8) = v;
    }
  }
}

// ---------------- launch ----------------

extern "C" void kernel_launch(void* const* d_in, const int* in_sizes, int n_in,
                              void* d_out, int out_size, void* d_ws, size_t ws_size,
                              hipStream_t stream) {
  (void)in_sizes; (void)n_in; (void)out_size; (void)ws_size;
  const float* x           = (const float*)d_in[0];
  const float* w_qkv       = (const float*)d_in[1];
  const float* q_bias      = (const float*)d_in[2];
  const float* v_bias      = (const float*)d_in[3];
  const float* logit_scale = (const float*)d_in[4];
  const float* cpb_w1      = (const float*)d_in[5];
  const float* cpb_b1      = (const float*)d_in[6];
  const float* cpb_w2      = (const float*)d_in[7];
  const float* proj_w      = (const float*)d_in[8];
  const float* proj_b      = (const float*)d_in[9];
  float* out = (float*)d_out;

  char* ws = (char*)d_ws;
  const size_t ARR_B  = 102760448;   // 32768*1568*2 = 100352*512*2
  const size_t WQT_B  = 1572864;     // 1536*512*2
  const size_t PJT_B  = 524288;      // 512*512*2
  const size_t T169_B = 10816;       // 169*16*4 (rounded)
  bf16*  Qa       = (bf16*)ws;
  bf16*  Ka       = (bf16*)(ws + ARR_B);
  bf16*  Va       = (bf16*)(ws + 2 * ARR_B);
  bf16*  xbf      = (bf16*)(ws + 3 * ARR_B);           // x bf16, then attn_out (gemm1 A)
  bf16*  wqkvT    = (bf16*)(ws + 4 * ARR_B);
  bf16*  projT    = (bf16*)(ws + 4 * ARR_B + WQT_B);
  float* tab169   = (float*)(ws + 4 * ARR_B + WQT_B + PJT_B);
  float* bias_sig = (float*)(ws + 4 * ARR_B + WQT_B + PJT_B + T169_B);

  cvt_x<<<2048, 256, 0, stream>>>(x, xbf, MROWS * 512 / 4);
  transpose_bf16<<<3072, 256, 0, stream>>>(w_qkv, wqkvT, 512, 1536);
  transpose_bf16<<<1024, 256, 0, stream>>>(proj_w, projT, 512, 512);
  cpb_mlp<<<169, 64, 0, stream>>>(cpb_w1, cpb_b1, cpb_w2, tab169);
  bias_expand<<<208, 256, 0, stream>>>(tab169, bias_sig);

  gemm128<0><<<784 * 12, 256, 0, stream>>>(xbf, wqkvT, nullptr, q_bias, v_bias,
                                           Qa, Ka, Va, 12, 512, 1536);
  attn_mfma<<<8192, 256, 0, stream>>>(Qa, Ka, Va, bias_sig, logit_scale, xbf);
  gemm128<1><<<784 * 4, 256, 0, stream>>>(xbf, projT, out, proj_b, nullptr,
                                          nullptr, nullptr, nullptr, 4, 512, 512);
}